// Round 4
// baseline (74.848 us; speedup 1.0000x reference)
//
#include <hip/hip_runtime.h>
#include <math.h>

#define N        512
#define DIM      256
#define NTHR     512            // 8 waves per block
#define APB      2              // anchors per block
#define NBLOCKS  (N / APB)      // 256
#define SCALING  10.0f
#define EPS      1e-12f
#define LOG2E    1.4426950408889634f

// v5: tail/micro shave on the v4 single-dispatch design.
//   Floor model (calibrated r0-r3): 40 us poison fill + ~28 us harness restore
//   nodes (~2.7 us/node) + ~6 us this kernel. This round shaves the kernel tail:
//   - distances pre-scaled by SCALING*log2(e) -> pair loop uses exp2f (raw
//     v_exp_f32, one fewer v_mul per triplet).
//   - publish/fold tail: wave 0 folds alone (lastflag via __shfl broadcast, no
//     extra block-wide __syncthreads); waves 1-7 exit immediately after publish.
//   - y loads hoisted above the distance pass (s_load latency hidden).
__device__ float        g_block_sum[NBLOCKS];
__device__ float        g_block_cnt[NBLOCKS];
__device__ unsigned int g_done = 0;   // zero at module load; self-resetting

__global__ __launch_bounds__(NTHR) void triplet_kernel(
    const float* __restrict__ feat, const int* __restrict__ y,
    float* __restrict__ out)
{
    __shared__ float d_a[APB][N];        // scaled distances for all rows
    __shared__ float pos_d[APB][N];
    __shared__ float neg_d[APB][N];
    __shared__ int   n_pos[APB], n_neg[APB];
    __shared__ float red_s[NTHR / 64];

    const int tid  = threadIdx.x;
    const int bid  = blockIdx.x;
    const int a0   = bid * APB;
    const int lane = tid & 63;
    const int wv   = tid >> 6;      // wave id 0..7
    const int seg  = lane & 15;     // position within 16-lane row group
    const int sub  = lane >> 4;     // which of 4 rows per pass

    if (tid < APB) { n_pos[tid] = 0; n_neg[tid] = 0; }

    // ---- label loads issued early; latency hides under the distance pass ----
    const int yj  = y[tid];
    const int ya0 = y[a0];
    const int ya1 = y[a0 + 1];

    // ---- anchor fragments in registers: float4 index seg + 16c ----
    const float4* f4 = reinterpret_cast<const float4*>(feat);
    float4 u0[4], u1[4];
    #pragma unroll
    for (int c = 0; c < 4; ++c) {
        u0[c] = f4[(a0    ) * (DIM / 4) + seg + 16 * c];
        u1[c] = f4[(a0 + 1) * (DIM / 4) + seg + 16 * c];
    }

    // ---- coalesced distance pass: wave wv owns rows [wv*64, wv*64+64) ----
    #pragma unroll 4
    for (int t = 0; t < 16; ++t) {
        const int r = (wv << 6) + (t << 2) + sub;
        const float4* rp = f4 + r * (DIM / 4);
        float acc0 = 0.0f, acc1 = 0.0f;
        #pragma unroll
        for (int c = 0; c < 4; ++c) {
            const float4 v = rp[seg + 16 * c];   // lanes 0..15 cover 256 B dense
            float e;
            e = v.x - u0[c].x; acc0 += e * e;
            e = v.y - u0[c].y; acc0 += e * e;
            e = v.z - u0[c].z; acc0 += e * e;
            e = v.w - u0[c].w; acc0 += e * e;
            e = v.x - u1[c].x; acc1 += e * e;
            e = v.y - u1[c].y; acc1 += e * e;
            e = v.z - u1[c].z; acc1 += e * e;
            e = v.w - u1[c].w; acc1 += e * e;
        }
        #pragma unroll
        for (int s = 1; s < 16; s <<= 1) {
            acc0 += __shfl_xor(acc0, s, 16);
            acc1 += __shfl_xor(acc1, s, 16);
        }
        if (seg == 0) {
            // pre-scale by SCALING*log2(e): pair loop becomes sub + exp2 + rcp
            d_a[0][r] = (SCALING * LOG2E) * sqrtf(fmaxf(acc0, EPS));
            d_a[1][r] = (SCALING * LOG2E) * sqrtf(fmaxf(acc1, EPS));
        }
    }
    __syncthreads();

    // ---- ballot-compacted classification (thread tid <-> row tid) ----
    const float d0 = d_a[0][tid];
    const float d1 = d_a[1][tid];
    const unsigned long long below = (1ull << lane) - 1ull;
    {
        const bool ip   = (yj == ya0) & (tid != a0);
        const bool ineg = (yj != ya0);
        const unsigned long long mp = __ballot(ip);
        const unsigned long long mn = __ballot(ineg);
        int bp = 0, bn = 0;
        if (lane == 0) {
            bp = atomicAdd(&n_pos[0], (int)__popcll(mp));
            bn = atomicAdd(&n_neg[0], (int)__popcll(mn));
        }
        bp = __shfl(bp, 0, 64);
        bn = __shfl(bn, 0, 64);
        if (ip)   pos_d[0][bp + (int)__popcll(mp & below)] = d0;
        if (ineg) neg_d[0][bn + (int)__popcll(mn & below)] = d0;
    }
    {
        const bool ip   = (yj == ya1) & (tid != a0 + 1);
        const bool ineg = (yj != ya1);
        const unsigned long long mp = __ballot(ip);
        const unsigned long long mn = __ballot(ineg);
        int bp = 0, bn = 0;
        if (lane == 0) {
            bp = atomicAdd(&n_pos[1], (int)__popcll(mp));
            bn = atomicAdd(&n_neg[1], (int)__popcll(mn));
        }
        bp = __shfl(bp, 0, 64);
        bn = __shfl(bn, 0, 64);
        if (ip)   pos_d[1][bp + (int)__popcll(mp & below)] = d1;
        if (ineg) neg_d[1][bn + (int)__popcll(mn & below)] = d1;
    }
    __syncthreads();

    // ---- sigmoid over valid (p, n) pairs: thread owns one negative ----
    float acc = 0.0f;
    int   cnt = 0;
    #pragma unroll
    for (int q = 0; q < APB; ++q) {
        const int np = n_pos[q];
        const int nn = n_neg[q];          // nn <= 511 < NTHR always
        cnt += np * nn;
        if (tid < nn) {
            const float dn = neg_d[q][tid];
            for (int p = 0; p < np; ++p) {
                const float e = exp2f(dn - pos_d[q][p]);   // 2^(dn'-dp') = e^-x
                acc += __fdividef(1.0f, 1.0f + e);
            }
        }
    }

    // ---- block reduce ----
    #pragma unroll
    for (int s = 32; s > 0; s >>= 1)
        acc += __shfl_down(acc, s, 64);
    if (lane == 0) red_s[wv] = acc;
    __syncthreads();

    // ---- wave 0 publishes and (if last) folds; waves 1-7 exit now ----
    if (wv == 0) {
        int lastflag = 0;
        if (lane == 0) {
            float t = 0.0f;
            #pragma unroll
            for (int w = 0; w < NTHR / 64; ++w) t += red_s[w];
            __hip_atomic_store(&g_block_sum[bid], t, __ATOMIC_RELAXED, __HIP_MEMORY_SCOPE_AGENT);
            __hip_atomic_store(&g_block_cnt[bid], (float)cnt, __ATOMIC_RELAXED, __HIP_MEMORY_SCOPE_AGENT);
            const unsigned int prev =
                __hip_atomic_fetch_add(&g_done, 1u, __ATOMIC_ACQ_REL, __HIP_MEMORY_SCOPE_AGENT);
            lastflag = (prev == NBLOCKS - 1) ? 1 : 0;
        }
        lastflag = __shfl(lastflag, 0, 64);

        if (lastflag) {
            // lane l folds partials l, l+64, l+128, l+192 (fixed order), then a
            // fixed shuffle tree: deterministic result.
            double s = 0.0, c = 0.0;
            #pragma unroll
            for (int k = 0; k < NBLOCKS / 64; ++k) {
                s += (double)__hip_atomic_load(&g_block_sum[lane + 64 * k],
                                               __ATOMIC_RELAXED, __HIP_MEMORY_SCOPE_AGENT);
                c += (double)__hip_atomic_load(&g_block_cnt[lane + 64 * k],
                                               __ATOMIC_RELAXED, __HIP_MEMORY_SCOPE_AGENT);
            }
            #pragma unroll
            for (int sh = 32; sh > 0; sh >>= 1) {
                s += __shfl_down(s, sh, 64);
                c += __shfl_down(c, sh, 64);
            }
            if (lane == 0) {
                out[0] = (float)(s / c);
                __hip_atomic_store(&g_done, 0u, __ATOMIC_RELAXED, __HIP_MEMORY_SCOPE_AGENT);
            }
        }
    }
}

extern "C" void kernel_launch(void* const* d_in, const int* in_sizes, int n_in,
                              void* d_out, int out_size, void* d_ws, size_t ws_size,
                              hipStream_t stream) {
    const float* feat = (const float*)d_in[0];
    // d_in[1] = logits: unused by the loss
    const int* y = (const int*)d_in[2];
    triplet_kernel<<<NBLOCKS, NTHR, 0, stream>>>(feat, y, (float*)d_out);
}